// Round 1
// 676.229 us; speedup vs baseline: 1.2091x; 1.2091x over previous
//
#include <hip/hip_runtime.h>
#include <math.h>

#define BB 8
#define NN 784
#define CC 768
#define HH 16
#define DD 48
#define SCALE 0.14433756729740643f    // 48^-0.5

// d_out layout (floats): out [B,N,C] | attn [B,H,N,N] | v [B,H,N,D]
#define ATTN_OFF ((size_t)BB*NN*CC)                  // 4816896
#define V_OFF (ATTN_OFF + (size_t)BB*HH*NN*NN)       // 83492864

// workspace layout (shorts/bf16)
#define WS_XB ((size_t)0)                            // x bf16 [6272][768]
#define WS_WB ((size_t)4816896)                      // Wq|Wk|Wv|Wproj bf16, 4x[768][768]
#define WS_QB (WS_WB + (size_t)4*589824)             // q bf16 [B,H,N,D]
#define WS_KB (WS_QB + (size_t)4816896)              // k bf16 [B,H,N,D]
#define WS_VT (WS_KB + (size_t)4816896)              // v^T bf16 [B,H,D,N]
#define WS_OB (WS_VT + (size_t)4816896)              // attn@v bf16 [B,N,C]

using bf16x8 = __attribute__((ext_vector_type(8))) short;
using f32x4  = __attribute__((ext_vector_type(4))) float;

__device__ __forceinline__ short f2bf(float f) {
    union { float f; unsigned u; } uf; uf.f = f;
    unsigned u = uf.u;
    return (short)((u + 0x7FFFu + ((u >> 16) & 1u)) >> 16);   // RNE
}
__device__ __forceinline__ bf16x8 bzero() {
    bf16x8 z = {0,0,0,0,0,0,0,0};
    return z;
}
__device__ __forceinline__ bf16x8 cvt8(float4 a, float4 b) {
    bf16x8 r;
    r[0]=f2bf(a.x); r[1]=f2bf(a.y); r[2]=f2bf(a.z); r[3]=f2bf(a.w);
    r[4]=f2bf(b.x); r[5]=f2bf(b.y); r[6]=f2bf(b.z); r[7]=f2bf(b.w);
    return r;
}
#define MFMA16(a,b,c) __builtin_amdgcn_mfma_f32_16x16x32_bf16((a),(b),(c),0,0,0)

// ---------------------------------------------------------------------------
// K0: cast x and the 4 weights to bf16 in ws. 4 floats / thread.
// ---------------------------------------------------------------------------
__global__ __launch_bounds__(256) void cast_kernel(
    const float* __restrict__ x, const float* __restrict__ Wq,
    const float* __restrict__ Wk, const float* __restrict__ Wv,
    const float* __restrict__ Wp, short* __restrict__ xb, short* __restrict__ wb)
{
    int idx = blockIdx.x * 256 + threadIdx.x;   // group of 4 elements
    const float* src;
    short* dst;
    if (idx < 1204224) {                         // x: 4816896/4
        src = x + (size_t)idx * 4;
        dst = xb + (size_t)idx * 4;
    } else {
        int j = idx - 1204224;
        int sel = j / 147456;                    // 589824/4
        size_t off = (size_t)(j % 147456) * 4;
        const float* W = (sel == 0) ? Wq : (sel == 1) ? Wk : (sel == 2) ? Wv : Wp;
        src = W + off;
        dst = wb + (size_t)sel * 589824 + off;
    }
    float4 v = *(const float4*)src;
    union { short s[4]; uint2 u; } o;
    o.s[0] = f2bf(v.x); o.s[1] = f2bf(v.y); o.s[2] = f2bf(v.z); o.s[3] = f2bf(v.w);
    *(uint2*)dst = o.u;
}

// ---------------------------------------------------------------------------
// K1: QKV projection, bf16 MFMA NT GEMM. M=6272, N=3*768, K=768.
// grid (49, 18); block 256 = 4 waves in 2x2; wave tile 64x64 (4x4 mfma tiles).
// Fragments loaded directly from global (L2-resident weights).
// q,k -> bf16 ws [B,H,N,D]; v -> fp32 d_out [B,H,N,D] + bf16 ws V^T [B,H,D,N].
// ---------------------------------------------------------------------------
__global__ __launch_bounds__(256) void qkv_mfma(
    const short* __restrict__ xb, const short* __restrict__ wb,
    short* __restrict__ qb, short* __restrict__ kb,
    float* __restrict__ vo, short* __restrict__ vt)
{
    const int t = threadIdx.x, l = t & 63, ww = t >> 6;
    const int quad = l >> 4, lc = l & 15;
    const int m0 = blockIdx.x * 128 + (ww >> 1) * 64;
    const int bn = blockIdx.y;
    const int wsel = bn / 6;
    const int colbase = (bn % 6) * 128 + (ww & 1) * 64;
    const short* W = wb + (size_t)wsel * 589824;

    f32x4 acc[4][4] = {};
    const short* arow = xb + (size_t)(m0 + lc) * 768 + quad * 8;
    const short* brow = W  + (size_t)(colbase + lc) * 768 + quad * 8;

    for (int k0 = 0; k0 < 768; k0 += 32) {
        bf16x8 af[4], bf[4];
#pragma unroll
        for (int i = 0; i < 4; i++) af[i] = *(const bf16x8*)(arow + (size_t)i * 16 * 768 + k0);
#pragma unroll
        for (int j = 0; j < 4; j++) bf[j] = *(const bf16x8*)(brow + (size_t)j * 16 * 768 + k0);
#pragma unroll
        for (int i = 0; i < 4; i++)
#pragma unroll
            for (int j = 0; j < 4; j++)
                acc[i][j] = MFMA16(af[i], bf[j], acc[i][j]);
    }

#pragma unroll
    for (int i = 0; i < 4; i++) {
#pragma unroll
        for (int j = 0; j < 4; j++) {
            const int o = colbase + j * 16 + lc;
            const int h = o / DD, d = o % DD;
#pragma unroll
            for (int r = 0; r < 4; r++) {
                const int m = m0 + i * 16 + quad * 4 + r;
                const int b = m / NN, n = m % NN;
                const size_t bhnd = (((size_t)b * HH + h) * NN + n) * DD + d;
                const float v = acc[i][j][r];
                if (wsel == 0)      qb[bhnd] = f2bf(v);
                else if (wsel == 1) kb[bhnd] = f2bf(v);
                else {
                    vo[bhnd] = v;
                    vt[((size_t)(b * HH + h) * DD + d) * NN + n] = f2bf(v);
                }
            }
        }
    }
}

// ---------------------------------------------------------------------------
// K2': fused QK^T (bf16 MFMA) + patch softmax + separable positional softmax
// (per-axis 55-entry exp tables; denominator factors as Sx(nx)*Sy(ny)) +
// gated blend + renorm + attn write (nontemporal) + PV MFMA straight from
// LDS against V^T. Eliminates the 315 MB attn re-read of the old K3.
// Block = 16-row strip of one (b,h); grid (49, 128).
// LDS: 16x812 fp32 strip (51.9 KB, stride 812 => rows 16B-aligned, ~2-way
// banks on the b128 PV reads) + 4x55 pos tables. 3 blocks/CU.
// ---------------------------------------------------------------------------
__global__ __launch_bounds__(256) void attn_pv_fused(
    const short* __restrict__ qb, const short* __restrict__ kb,
    const short* __restrict__ vt,
    const float* __restrict__ W_pos, const float* __restrict__ b_pos,
    const float* __restrict__ gating, float* __restrict__ attn,
    short* __restrict__ ob)
{
    const int t = threadIdx.x, l = t & 63, ww = t >> 6;
    const int quad = l >> 4, lc = l & 15;
    const int bh = blockIdx.y, b = bh >> 4, h = bh & 15;
    const int row0 = blockIdx.x * 16;

    __shared__ float Sbuf[16][812];
    __shared__ float lxs[55], lys[55], fxs[55], fys[55];

    // zero-pad cols 784..799 (PV k-loop reads through 799)
    Sbuf[t >> 4][784 + (t & 15)] = 0.f;

    // ---- phase A: S strip = q(16x48) @ k^T, col-tiles split across waves
    const short* qrow = qb + ((size_t)bh * NN + row0 + lc) * DD;
    bf16x8 qf0 = *(const bf16x8*)(qrow + quad * 8);
    bf16x8 qf1 = (quad < 2) ? *(const bf16x8*)(qrow + 32 + quad * 8) : bzero();

    for (int ct = ww; ct < 49; ct += 4) {
        const int c0 = ct * 16;
        const short* krow = kb + ((size_t)bh * NN + c0 + lc) * DD;
        bf16x8 kf0 = *(const bf16x8*)(krow + quad * 8);
        bf16x8 kf1 = (quad < 2) ? *(const bf16x8*)(krow + 32 + quad * 8) : bzero();
        f32x4 cc = {0.f, 0.f, 0.f, 0.f};
        cc = MFMA16(qf0, kf0, cc);
        cc = MFMA16(qf1, kf1, cc);
#pragma unroll
        for (int r = 0; r < 4; r++)
            Sbuf[quad * 4 + r][c0 + lc] = cc[r] * SCALE;
    }

    // ---- separable positional logits: lx(d)=w0*d+w2*d^2, ly(d)=w1*d+w2*d^2
    // (b_pos cancels in softmax; exp(pl) = fx(dx)*fy(dy), denom = Sx*Sy)
    const float w0 = W_pos[h * 3], w1 = W_pos[h * 3 + 1], w2 = W_pos[h * 3 + 2];
    if (t < 55) {
        const float d = (float)(t - 27);
        lxs[t] = fmaf(w2, d * d, w0 * d);
    } else if (t >= 64 && t < 119) {
        const float d = (float)(t - 91);
        lys[t - 64] = fmaf(w2, d * d, w1 * d);
    }

    __syncthreads();

    // ---- per-axis max-normalized exp tables (overflow-safe: fx,fy <= 1)
    if (t < 55) {
        float m = lxs[0];
#pragma unroll
        for (int i = 1; i < 55; i++) m = fmaxf(m, lxs[i]);
        fxs[t] = __expf(lxs[t] - m);
    } else if (t >= 64 && t < 119) {
        float m = lys[0];
#pragma unroll
        for (int i = 1; i < 55; i++) m = fmaxf(m, lys[i]);
        fys[t - 64] = __expf(lys[t - 64] - m);
    }

    // ---- patch softmax over the strip (row fully owned by one 16-lane group)
    const int r = t >> 4, c = t & 15;
    const int nrow = row0 + r;
    const int nx = nrow % 28, ny = nrow / 28;

    float sm = -1e30f;
#pragma unroll 7
    for (int s = 0; s < 49; s++) sm = fmaxf(sm, Sbuf[r][c + 16 * s]);
    sm = fmaxf(sm, __shfl_xor(sm, 1));
    sm = fmaxf(sm, __shfl_xor(sm, 2));
    sm = fmaxf(sm, __shfl_xor(sm, 4));
    sm = fmaxf(sm, __shfl_xor(sm, 8));
    float se = 0.f;
#pragma unroll 7
    for (int s = 0; s < 49; s++) {
        const float e = __expf(Sbuf[r][c + 16 * s] - sm);
        Sbuf[r][c + 16 * s] = e;
        se += e;
    }
    se += __shfl_xor(se, 1);
    se += __shfl_xor(se, 2);
    se += __shfl_xor(se, 4);
    se += __shfl_xor(se, 8);
    const float inv = 1.f / se;
    const float g = 1.f / (1.f + __expf(-gating[h]));

    __syncthreads();   // fxs/fys visible

    // ---- positional denominator: Sx(nx)*Sy(ny), 28-term sums from tables
    float Sx = 0.f, Sy = 0.f;
#pragma unroll
    for (int mx = 0; mx < 28; mx++) Sx += fxs[mx - nx + 27];
#pragma unroll
    for (int my = 0; my < 28; my++) Sy += fys[my - ny + 27];
    const float pinv = 1.f / (Sx * Sy);

    // ---- blend with positional softmax, accumulate row sum
    float sa = 0.f;
    {
        int mx = c, my = 0;                       // m = c + 16*s, incremental
#pragma unroll 7
        for (int s = 0; s < 49; s++) {
            const int m = c + 16 * s;
            const float pos = fxs[mx - nx + 27] * fys[my - ny + 27] * pinv;
            const float a = (1.f - g) * Sbuf[r][m] * inv + g * pos;
            Sbuf[r][m] = a;
            sa += a;
            mx += 16;
            if (mx >= 28) { mx -= 28; my++; }
        }
    }
    sa += __shfl_xor(sa, 1);
    sa += __shfl_xor(sa, 2);
    sa += __shfl_xor(sa, 4);
    sa += __shfl_xor(sa, 8);
    const float inv2 = 1.f / sa;

    // ---- renorm, write attn (streaming: nothing re-reads it), keep in LDS
    float* arow = attn + ((size_t)bh * NN + nrow) * NN;
#pragma unroll 7
    for (int s = 0; s < 49; s++) {
        const float val = Sbuf[r][c + 16 * s] * inv2;
        __builtin_nontemporal_store(val, arow + c + 16 * s);
        Sbuf[r][c + 16 * s] = val;
    }

    __syncthreads();   // final attn strip visible to all waves

    // ---- PV: O(16x48) = attn(16x784) @ v(784x48), d-tile per wave (0..2).
    // Same k-order + same fp32->bf16 conversion point as the old K3.
    if (ww < 3) {
        const short* vrow = vt + ((size_t)bh * DD + ww * 16 + lc) * NN;
        f32x4 acc = {0.f, 0.f, 0.f, 0.f};
        for (int kt = 0; kt < 25; kt++) {
            const int k0 = kt * 32 + quad * 8;
            bf16x8 af, bf;
            if (k0 < NN) {
                float4 a0 = *(const float4*)&Sbuf[lc][k0];
                float4 a1 = *(const float4*)&Sbuf[lc][k0 + 4];
                af = cvt8(a0, a1);
                bf = *(const bf16x8*)(vrow + k0);
            } else {
                af = bzero();
                bf = bzero();
            }
            acc = MFMA16(af, bf, acc);
        }
        const int d = h * DD + ww * 16 + lc;
#pragma unroll
        for (int rr = 0; rr < 4; rr++) {
            const int rowi = row0 + quad * 4 + rr;
            ob[((size_t)b * NN + rowi) * CC + d] = f2bf(acc[rr]);
        }
    }
}

// ---------------------------------------------------------------------------
// K4: out = ob @ Wproj^T + bias, bf16 MFMA NT GEMM. M=6272, N=768, K=768.
// grid (49, 6); same structure as K1; fp32 output.
// ---------------------------------------------------------------------------
__global__ __launch_bounds__(256) void proj_mfma(
    const short* __restrict__ ob, const short* __restrict__ wb,
    const float* __restrict__ bias, float* __restrict__ out)
{
    const int t = threadIdx.x, l = t & 63, ww = t >> 6;
    const int quad = l >> 4, lc = l & 15;
    const int m0 = blockIdx.x * 128 + (ww >> 1) * 64;
    const int colbase = blockIdx.y * 128 + (ww & 1) * 64;
    const short* W = wb + (size_t)3 * 589824;   // Wproj

    f32x4 acc[4][4] = {};
    const short* arow = ob + (size_t)(m0 + lc) * 768 + quad * 8;
    const short* brow = W  + (size_t)(colbase + lc) * 768 + quad * 8;

    for (int k0 = 0; k0 < 768; k0 += 32) {
        bf16x8 af[4], bf[4];
#pragma unroll
        for (int i = 0; i < 4; i++) af[i] = *(const bf16x8*)(arow + (size_t)i * 16 * 768 + k0);
#pragma unroll
        for (int j = 0; j < 4; j++) bf[j] = *(const bf16x8*)(brow + (size_t)j * 16 * 768 + k0);
#pragma unroll
        for (int i = 0; i < 4; i++)
#pragma unroll
            for (int j = 0; j < 4; j++)
                acc[i][j] = MFMA16(af[i], bf[j], acc[i][j]);
    }

#pragma unroll
    for (int i = 0; i < 4; i++) {
#pragma unroll
        for (int j = 0; j < 4; j++) {
            const int o = colbase + j * 16 + lc;
            const float bo = bias[o];
#pragma unroll
            for (int r = 0; r < 4; r++) {
                const int m = m0 + i * 16 + quad * 4 + r;
                out[(size_t)m * CC + o] = acc[i][j][r] + bo;
            }
        }
    }
}

extern "C" void kernel_launch(void* const* d_in, const int* in_sizes, int n_in,
                              void* d_out, int out_size, void* d_ws, size_t ws_size,
                              hipStream_t stream)
{
    const float* x      = (const float*)d_in[0];
    const float* Wq     = (const float*)d_in[1];
    const float* Wk     = (const float*)d_in[2];
    const float* Wv     = (const float*)d_in[3];
    const float* Wproj  = (const float*)d_in[4];
    const float* b_proj = (const float*)d_in[5];
    const float* W_pos  = (const float*)d_in[6];
    const float* b_pos  = (const float*)d_in[7];
    const float* gating = (const float*)d_in[8];

    float* out  = (float*)d_out;
    short* ws   = (short*)d_ws;

    short* xb = ws + WS_XB;
    short* wb = ws + WS_WB;
    short* qb = ws + WS_QB;
    short* kb = ws + WS_KB;
    short* vt = ws + WS_VT;
    short* ob = ws + WS_OB;
    float* attn = out + ATTN_OFF;
    float* vout = out + V_OFF;

    hipLaunchKernelGGL(cast_kernel, dim3(7008), dim3(256), 0, stream,
                       x, Wq, Wk, Wv, Wproj, xb, wb);
    hipLaunchKernelGGL(qkv_mfma, dim3(49, 18), dim3(256), 0, stream,
                       xb, wb, qb, kb, vout, vt);
    hipLaunchKernelGGL(attn_pv_fused, dim3(49, 128), dim3(256), 0, stream,
                       qb, kb, vt, W_pos, b_pos, gating, attn, ob);
    hipLaunchKernelGGL(proj_mfma, dim3(49, 6), dim3(256), 0, stream,
                       ob, wb, b_proj, out);
}

// Round 2
// 638.288 us; speedup vs baseline: 1.2809x; 1.0594x over previous
//
#include <hip/hip_runtime.h>
#include <math.h>

#define BB 8
#define NN 784
#define CC 768
#define HH 16
#define DD 48
#define SCALE 0.14433756729740643f    // 48^-0.5

// d_out layout (floats): out [B,N,C] | attn [B,H,N,N] | v [B,H,N,D]
#define ATTN_OFF ((size_t)BB*NN*CC)                  // 4816896
#define V_OFF (ATTN_OFF + (size_t)BB*HH*NN*NN)       // 83492864

// workspace layout (shorts/bf16)
#define WS_XB ((size_t)0)                            // x bf16 [6272][768]
#define WS_WB ((size_t)4816896)                      // Wq|Wk|Wv|Wproj bf16, 4x[768][768]
#define WS_QB (WS_WB + (size_t)4*589824)             // q bf16 [B,H,N,D]
#define WS_KB (WS_QB + (size_t)4816896)              // k bf16 [B,H,N,D]
#define WS_VT (WS_KB + (size_t)4816896)              // v^T bf16 [B,H,D,N]
#define WS_OB (WS_VT + (size_t)4816896)              // attn@v bf16 [B,N,C]

using bf16x8 = __attribute__((ext_vector_type(8))) short;
using f32x4  = __attribute__((ext_vector_type(4))) float;

__device__ __forceinline__ short f2bf(float f) {
    union { float f; unsigned u; } uf; uf.f = f;
    unsigned u = uf.u;
    return (short)((u + 0x7FFFu + ((u >> 16) & 1u)) >> 16);   // RNE
}
__device__ __forceinline__ bf16x8 bzero() {
    bf16x8 z = {0,0,0,0,0,0,0,0};
    return z;
}
__device__ __forceinline__ bf16x8 cvt8(float4 a, float4 b) {
    bf16x8 r;
    r[0]=f2bf(a.x); r[1]=f2bf(a.y); r[2]=f2bf(a.z); r[3]=f2bf(a.w);
    r[4]=f2bf(b.x); r[5]=f2bf(b.y); r[6]=f2bf(b.z); r[7]=f2bf(b.w);
    return r;
}
#define MFMA16(a,b,c) __builtin_amdgcn_mfma_f32_16x16x32_bf16((a),(b),(c),0,0,0)

// ---------------------------------------------------------------------------
// K0: cast x and the 4 weights to bf16 in ws. 4 floats / thread.
// ---------------------------------------------------------------------------
__global__ __launch_bounds__(256) void cast_kernel(
    const float* __restrict__ x, const float* __restrict__ Wq,
    const float* __restrict__ Wk, const float* __restrict__ Wv,
    const float* __restrict__ Wp, short* __restrict__ xb, short* __restrict__ wb)
{
    int idx = blockIdx.x * 256 + threadIdx.x;   // group of 4 elements
    const float* src;
    short* dst;
    if (idx < 1204224) {                         // x: 4816896/4
        src = x + (size_t)idx * 4;
        dst = xb + (size_t)idx * 4;
    } else {
        int j = idx - 1204224;
        int sel = j / 147456;                    // 589824/4
        size_t off = (size_t)(j % 147456) * 4;
        const float* W = (sel == 0) ? Wq : (sel == 1) ? Wk : (sel == 2) ? Wv : Wp;
        src = W + off;
        dst = wb + (size_t)sel * 589824 + off;
    }
    float4 v = *(const float4*)src;
    union { short s[4]; uint2 u; } o;
    o.s[0] = f2bf(v.x); o.s[1] = f2bf(v.y); o.s[2] = f2bf(v.z); o.s[3] = f2bf(v.w);
    *(uint2*)dst = o.u;
}

// ---------------------------------------------------------------------------
// K1: QKV projection, bf16 MFMA NT GEMM. M=6272, N=3*768, K=768.
// grid (49, 18); block 256 = 4 waves in 2x2; wave tile 64x64 (4x4 mfma tiles).
// Fragments loaded directly from global (L2-resident weights).
// q,k -> bf16 ws [B,H,N,D]; v -> fp32 d_out [B,H,N,D] + bf16 ws V^T [B,H,D,N].
// ---------------------------------------------------------------------------
__global__ __launch_bounds__(256) void qkv_mfma(
    const short* __restrict__ xb, const short* __restrict__ wb,
    short* __restrict__ qb, short* __restrict__ kb,
    float* __restrict__ vo, short* __restrict__ vt)
{
    const int t = threadIdx.x, l = t & 63, ww = t >> 6;
    const int quad = l >> 4, lc = l & 15;
    const int m0 = blockIdx.x * 128 + (ww >> 1) * 64;
    const int bn = blockIdx.y;
    const int wsel = bn / 6;
    const int colbase = (bn % 6) * 128 + (ww & 1) * 64;
    const short* W = wb + (size_t)wsel * 589824;

    f32x4 acc[4][4] = {};
    const short* arow = xb + (size_t)(m0 + lc) * 768 + quad * 8;
    const short* brow = W  + (size_t)(colbase + lc) * 768 + quad * 8;

    for (int k0 = 0; k0 < 768; k0 += 32) {
        bf16x8 af[4], bf[4];
#pragma unroll
        for (int i = 0; i < 4; i++) af[i] = *(const bf16x8*)(arow + (size_t)i * 16 * 768 + k0);
#pragma unroll
        for (int j = 0; j < 4; j++) bf[j] = *(const bf16x8*)(brow + (size_t)j * 16 * 768 + k0);
#pragma unroll
        for (int i = 0; i < 4; i++)
#pragma unroll
            for (int j = 0; j < 4; j++)
                acc[i][j] = MFMA16(af[i], bf[j], acc[i][j]);
    }

#pragma unroll
    for (int i = 0; i < 4; i++) {
#pragma unroll
        for (int j = 0; j < 4; j++) {
            const int o = colbase + j * 16 + lc;
            const int h = o / DD, d = o % DD;
#pragma unroll
            for (int r = 0; r < 4; r++) {
                const int m = m0 + i * 16 + quad * 4 + r;
                const int b = m / NN, n = m % NN;
                const size_t bhnd = (((size_t)b * HH + h) * NN + n) * DD + d;
                const float v = acc[i][j][r];
                if (wsel == 0)      qb[bhnd] = f2bf(v);
                else if (wsel == 1) kb[bhnd] = f2bf(v);
                else {
                    __builtin_nontemporal_store(v, vo + bhnd);   // nothing re-reads vo
                    vt[((size_t)(b * HH + h) * DD + d) * NN + n] = f2bf(v);
                }
            }
        }
    }
}

// ---------------------------------------------------------------------------
// K2': fused QK^T + patch softmax + separable positional softmax + blend +
// attn write + PV, all in one block per 16-row strip. grid (49, 128).
// This revision:
//  - row-max hoisted into phase A (register pmax + tiny LDS combine):
//    deletes the 49-iter max pass.
//  - renorm pass deleted: blend sums to 1 by construction ((1-g)+g), the
//    1/sum differs from 1 by ~1e-6 -> write blend directly (fused with the
//    nontemporal attn store).
//  - PV K-split across all 4 waves (each kt-range converted to bf16 once,
//    not 3x) + cross-wave reduce through LDS partials aliased over Sbuf.
//  - phase A 1-deep prefetch of next K fragments (hide L2 latency).
// LDS: 16x812 fp32 Sbuf + 4x55 tables + 16x4 pmax = 53.1 KB -> 3 blocks/CU.
// ---------------------------------------------------------------------------
__global__ __launch_bounds__(256) void attn_pv_fused(
    const short* __restrict__ qb, const short* __restrict__ kb,
    const short* __restrict__ vt,
    const float* __restrict__ W_pos, const float* __restrict__ b_pos,
    const float* __restrict__ gating, float* __restrict__ attn,
    short* __restrict__ ob)
{
    const int t = threadIdx.x, l = t & 63, ww = t >> 6;
    const int quad = l >> 4, lc = l & 15;
    const int bh = blockIdx.y, b = bh >> 4, h = bh & 15;
    const int row0 = blockIdx.x * 16;

    __shared__ __align__(16) float Sbuf[16][812];
    __shared__ float lxs[55], lys[55], fxs[55], fys[55];
    __shared__ float pmws[16][4];

    // zero-pad cols 784..799 (PV k-loop reads through 799)
    Sbuf[t >> 4][784 + (t & 15)] = 0.f;

    // ---- phase A: S strip = q(16x48) @ k^T, col-tiles split across waves,
    // next-tile K fragments prefetched, per-row max tracked in registers.
    const short* qrow = qb + ((size_t)bh * NN + row0 + lc) * DD;
    bf16x8 qf0 = *(const bf16x8*)(qrow + quad * 8);
    bf16x8 qf1 = (quad < 2) ? *(const bf16x8*)(qrow + 32 + quad * 8) : bzero();

    float pmax[4] = {-3e38f, -3e38f, -3e38f, -3e38f};
    {
        int ct = ww;
        const short* krow = kb + ((size_t)bh * NN + ct * 16 + lc) * DD;
        bf16x8 kf0 = *(const bf16x8*)(krow + quad * 8);
        bf16x8 kf1 = (quad < 2) ? *(const bf16x8*)(krow + 32 + quad * 8) : bzero();
        while (ct < 49) {
            const int nct = ct + 4;
            bf16x8 nk0 = bzero(), nk1 = bzero();
            if (nct < 49) {
                const short* nrow = kb + ((size_t)bh * NN + nct * 16 + lc) * DD;
                nk0 = *(const bf16x8*)(nrow + quad * 8);
                nk1 = (quad < 2) ? *(const bf16x8*)(nrow + 32 + quad * 8) : bzero();
            }
            f32x4 cc = {0.f, 0.f, 0.f, 0.f};
            cc = MFMA16(qf0, kf0, cc);
            cc = MFMA16(qf1, kf1, cc);
            const int c0 = ct * 16;
#pragma unroll
            for (int r = 0; r < 4; r++) {
                Sbuf[quad * 4 + r][c0 + lc] = cc[r] * SCALE;
                pmax[r] = fmaxf(pmax[r], cc[r]);
            }
            kf0 = nk0; kf1 = nk1; ct = nct;
        }
    }
    // per-row partial max across the 16 cols this quad-group owns
#pragma unroll
    for (int r = 0; r < 4; r++) {
        float v = pmax[r];
        v = fmaxf(v, __shfl_xor(v, 1));
        v = fmaxf(v, __shfl_xor(v, 2));
        v = fmaxf(v, __shfl_xor(v, 4));
        v = fmaxf(v, __shfl_xor(v, 8));
        if (lc == 0) pmws[quad * 4 + r][ww] = v;
    }

    // ---- separable positional logits: lx(d)=w0*d+w2*d^2, ly(d)=w1*d+w2*d^2
    // (b_pos cancels in softmax; exp(pl) = fx(dx)*fy(dy), denom = Sx*Sy)
    const float w0 = W_pos[h * 3], w1 = W_pos[h * 3 + 1], w2 = W_pos[h * 3 + 2];
    if (t < 55) {
        const float d = (float)(t - 27);
        lxs[t] = fmaf(w2, d * d, w0 * d);
    } else if (t >= 64 && t < 119) {
        const float d = (float)(t - 91);
        lys[t - 64] = fmaf(w2, d * d, w1 * d);
    }

    __syncthreads();

    // ---- per-axis max-normalized exp tables (overflow-safe: fx,fy <= 1)
    if (t < 55) {
        float m = lxs[0];
#pragma unroll
        for (int i = 1; i < 55; i++) m = fmaxf(m, lxs[i]);
        fxs[t] = __expf(lxs[t] - m);
    } else if (t >= 64 && t < 119) {
        float m = lys[0];
#pragma unroll
        for (int i = 1; i < 55; i++) m = fmaxf(m, lys[i]);
        fys[t - 64] = __expf(lys[t - 64] - m);
    }

    // ---- patch softmax: max from phase-A partials, then exp+sum pass
    const int r = t >> 4, c = t & 15;
    const int nrow = row0 + r;
    const int nx = nrow % 28, ny = nrow / 28;

    const float sm = SCALE * fmaxf(fmaxf(pmws[r][0], pmws[r][1]),
                                   fmaxf(pmws[r][2], pmws[r][3]));
    float se = 0.f;
#pragma unroll 7
    for (int s = 0; s < 49; s++) {
        const float e = __expf(Sbuf[r][c + 16 * s] - sm);
        Sbuf[r][c + 16 * s] = e;
        se += e;
    }
    se += __shfl_xor(se, 1);
    se += __shfl_xor(se, 2);
    se += __shfl_xor(se, 4);
    se += __shfl_xor(se, 8);
    const float inv = 1.f / se;
    const float g = 1.f / (1.f + __expf(-gating[h]));

    __syncthreads();   // fxs/fys visible

    // ---- positional denominator: Sx(nx)*Sy(ny), 28-term sums from tables
    float Sx = 0.f, Sy = 0.f;
#pragma unroll
    for (int mx = 0; mx < 28; mx++) Sx += fxs[mx - nx + 27];
#pragma unroll
    for (int my = 0; my < 28; my++) Sy += fys[my - ny + 27];
    const float ginv = (1.f - g) * inv;          // patch coefficient
    const float gp = g / (Sx * Sy);              // pos coefficient

    // ---- blend + write attn (blend sums to 1: renorm division dropped,
    // error ~1e-6 << tolerance). Keep blended row in LDS for PV.
    float* arow = attn + ((size_t)bh * NN + nrow) * NN;
    {
        int mx = c, my = 0;                       // m = c + 16*s, incremental
#pragma unroll 7
        for (int s = 0; s < 49; s++) {
            const int m = c + 16 * s;
            const float a = fmaf(Sbuf[r][m], ginv,
                                 fxs[mx - nx + 27] * fys[my - ny + 27] * gp);
            Sbuf[r][m] = a;
            __builtin_nontemporal_store(a, arow + m);
            mx += 16;
            if (mx >= 28) { mx -= 28; my++; }
        }
    }

    __syncthreads();   // final attn strip visible to all waves

    // ---- PV: O(16x48) = attn(16x784) @ v(784x48). K-split: wave w handles
    // kt-range (each column converted to bf16 exactly once), then cross-wave
    // reduce via LDS partials aliased over the now-dead Sbuf.
    const short* vbase = vt + (size_t)bh * DD * NN;
    f32x4 acc[3] = {};
    {
        const int kt0 = ww * 6;                   // 6,6,6,7 split of 25
        const int kt1 = (ww == 3) ? 25 : kt0 + 6;
        for (int kt = kt0; kt < kt1; kt++) {
            const int k0 = kt * 32 + quad * 8;
            float4 a0 = *(const float4*)&Sbuf[lc][k0];
            float4 a1 = *(const float4*)&Sbuf[lc][k0 + 4];
            bf16x8 af = cvt8(a0, a1);
#pragma unroll
            for (int j = 0; j < 3; j++) {
                bf16x8 bf = (k0 < NN)
                    ? *(const bf16x8*)(vbase + (size_t)(j * 16 + lc) * NN + k0)
                    : bzero();
                acc[j] = MFMA16(af, bf, acc[j]);
            }
        }
    }

    __syncthreads();   // everyone done reading Sbuf; safe to alias

    float* Pacc = &Sbuf[0][0];                    // [3 waves][3 j][64 lanes][4]
    if (ww > 0) {
#pragma unroll
        for (int j = 0; j < 3; j++)
            *(f32x4*)&Pacc[(((ww - 1) * 3 + j) * 64 + l) * 4] = acc[j];
    }

    __syncthreads();

    if (ww == 0) {
#pragma unroll
        for (int j = 0; j < 3; j++) {
#pragma unroll
            for (int w = 0; w < 3; w++)
                acc[j] += *(const f32x4*)&Pacc[((w * 3 + j) * 64 + l) * 4];
            const int d = h * DD + j * 16 + lc;
#pragma unroll
            for (int rr = 0; rr < 4; rr++) {
                const int rowi = row0 + quad * 4 + rr;
                ob[((size_t)b * NN + rowi) * CC + d] = f2bf(acc[j][rr]);
            }
        }
    }
}

// ---------------------------------------------------------------------------
// K4: out = ob @ Wproj^T + bias, bf16 MFMA NT GEMM. M=6272, N=768, K=768.
// grid (49, 6); same structure as K1; fp32 output (nontemporal).
// ---------------------------------------------------------------------------
__global__ __launch_bounds__(256) void proj_mfma(
    const short* __restrict__ ob, const short* __restrict__ wb,
    const float* __restrict__ bias, float* __restrict__ out)
{
    const int t = threadIdx.x, l = t & 63, ww = t >> 6;
    const int quad = l >> 4, lc = l & 15;
    const int m0 = blockIdx.x * 128 + (ww >> 1) * 64;
    const int colbase = blockIdx.y * 128 + (ww & 1) * 64;
    const short* W = wb + (size_t)3 * 589824;   // Wproj

    f32x4 acc[4][4] = {};
    const short* arow = ob + (size_t)(m0 + lc) * 768 + quad * 8;
    const short* brow = W  + (size_t)(colbase + lc) * 768 + quad * 8;

    for (int k0 = 0; k0 < 768; k0 += 32) {
        bf16x8 af[4], bf[4];
#pragma unroll
        for (int i = 0; i < 4; i++) af[i] = *(const bf16x8*)(arow + (size_t)i * 16 * 768 + k0);
#pragma unroll
        for (int j = 0; j < 4; j++) bf[j] = *(const bf16x8*)(brow + (size_t)j * 16 * 768 + k0);
#pragma unroll
        for (int i = 0; i < 4; i++)
#pragma unroll
            for (int j = 0; j < 4; j++)
                acc[i][j] = MFMA16(af[i], bf[j], acc[i][j]);
    }

#pragma unroll
    for (int i = 0; i < 4; i++) {
#pragma unroll
        for (int j = 0; j < 4; j++) {
            const int o = colbase + j * 16 + lc;
            const float bo = bias[o];
#pragma unroll
            for (int r = 0; r < 4; r++) {
                const int m = m0 + i * 16 + quad * 4 + r;
                __builtin_nontemporal_store(acc[i][j][r] + bo, out + (size_t)m * CC + o);
            }
        }
    }
}

extern "C" void kernel_launch(void* const* d_in, const int* in_sizes, int n_in,
                              void* d_out, int out_size, void* d_ws, size_t ws_size,
                              hipStream_t stream)
{
    const float* x      = (const float*)d_in[0];
    const float* Wq     = (const float*)d_in[1];
    const float* Wk     = (const float*)d_in[2];
    const float* Wv     = (const float*)d_in[3];
    const float* Wproj  = (const float*)d_in[4];
    const float* b_proj = (const float*)d_in[5];
    const float* W_pos  = (const float*)d_in[6];
    const float* b_pos  = (const float*)d_in[7];
    const float* gating = (const float*)d_in[8];

    float* out  = (float*)d_out;
    short* ws   = (short*)d_ws;

    short* xb = ws + WS_XB;
    short* wb = ws + WS_WB;
    short* qb = ws + WS_QB;
    short* kb = ws + WS_KB;
    short* vt = ws + WS_VT;
    short* ob = ws + WS_OB;
    float* attn = out + ATTN_OFF;
    float* vout = out + V_OFF;

    hipLaunchKernelGGL(cast_kernel, dim3(7008), dim3(256), 0, stream,
                       x, Wq, Wk, Wv, Wproj, xb, wb);
    hipLaunchKernelGGL(qkv_mfma, dim3(49, 18), dim3(256), 0, stream,
                       xb, wb, qb, kb, vout, vt);
    hipLaunchKernelGGL(attn_pv_fused, dim3(49, 128), dim3(256), 0, stream,
                       qb, kb, vt, W_pos, b_pos, gating, attn, ob);
    hipLaunchKernelGGL(proj_mfma, dim3(49, 6), dim3(256), 0, stream,
                       ob, wb, b_proj, out);
}

// Round 4
// 628.961 us; speedup vs baseline: 1.2999x; 1.0148x over previous
//
#include <hip/hip_runtime.h>
#include <math.h>

#define BB 8
#define NN 784
#define CC 768
#define HH 16
#define DD 48
#define SCALE 0.14433756729740643f    // 48^-0.5

// d_out layout (floats): out [B,N,C] | attn [B,H,N,N] | v [B,H,N,D]
#define ATTN_OFF ((size_t)BB*NN*CC)                  // 4816896
#define V_OFF (ATTN_OFF + (size_t)BB*HH*NN*NN)       // 83492864

// workspace layout (shorts/bf16)
#define WS_XB ((size_t)0)                            // x bf16 [6272][768]
#define WS_WB ((size_t)4816896)                      // Wq|Wk|Wv|Wproj bf16, 4x[768][768]
#define WS_QB (WS_WB + (size_t)4*589824)             // q bf16 [B,H,N,D]
#define WS_KB (WS_QB + (size_t)4816896)              // k bf16 [B,H,N,D]
#define WS_VT (WS_KB + (size_t)4816896)              // v^T bf16 [B,H,D,N]
#define WS_OB (WS_VT + (size_t)4816896)              // attn@v bf16 [B,N,C]

using bf16x8 = __attribute__((ext_vector_type(8))) short;
using f32x4  = __attribute__((ext_vector_type(4))) float;

__device__ __forceinline__ short f2bf(float f) {
    union { float f; unsigned u; } uf; uf.f = f;
    unsigned u = uf.u;
    return (short)((u + 0x7FFFu + ((u >> 16) & 1u)) >> 16);   // RNE
}
__device__ __forceinline__ bf16x8 bzero() {
    bf16x8 z = {0,0,0,0,0,0,0,0};
    return z;
}
__device__ __forceinline__ bf16x8 cvt8v(f32x4 a, f32x4 b) {
    bf16x8 r;
    r[0]=f2bf(a[0]); r[1]=f2bf(a[1]); r[2]=f2bf(a[2]); r[3]=f2bf(a[3]);
    r[4]=f2bf(b[0]); r[5]=f2bf(b[1]); r[6]=f2bf(b[2]); r[7]=f2bf(b[3]);
    return r;
}
#define MFMA16(a,b,c) __builtin_amdgcn_mfma_f32_16x16x32_bf16((a),(b),(c),0,0,0)

// ---------------------------------------------------------------------------
// K0: cast x and the 4 weights to bf16 in ws. 4 floats / thread.
// ---------------------------------------------------------------------------
__global__ __launch_bounds__(256) void cast_kernel(
    const float* __restrict__ x, const float* __restrict__ Wq,
    const float* __restrict__ Wk, const float* __restrict__ Wv,
    const float* __restrict__ Wp, short* __restrict__ xb, short* __restrict__ wb)
{
    int idx = blockIdx.x * 256 + threadIdx.x;   // group of 4 elements
    const float* src;
    short* dst;
    if (idx < 1204224) {                         // x: 4816896/4
        src = x + (size_t)idx * 4;
        dst = xb + (size_t)idx * 4;
    } else {
        int j = idx - 1204224;
        int sel = j / 147456;                    // 589824/4
        size_t off = (size_t)(j % 147456) * 4;
        const float* W = (sel == 0) ? Wq : (sel == 1) ? Wk : (sel == 2) ? Wv : Wp;
        src = W + off;
        dst = wb + (size_t)sel * 589824 + off;
    }
    f32x4 v = *(const f32x4*)src;
    union { short s[4]; uint2 u; } o;
    o.s[0] = f2bf(v[0]); o.s[1] = f2bf(v[1]); o.s[2] = f2bf(v[2]); o.s[3] = f2bf(v[3]);
    *(uint2*)dst = o.u;
}

// ---------------------------------------------------------------------------
// K1: QKV projection, bf16 MFMA NT GEMM. M=6272, N=3*768, K=768.
// 1-D grid 882, A-panel-major order + bijective XCD chunk swizzle: the 18
// blocks sharing one 128-row A-panel land on the same XCD L2 (per-XCD
// working set: 1 A-panel + 18 B-panels ~= 3.7 MB < 4 MB).
// q,k -> bf16 ws [B,H,N,D]; v -> fp32 d_out [B,H,N,D] + bf16 ws V^T [B,H,D,N].
// ---------------------------------------------------------------------------
__global__ __launch_bounds__(256) void qkv_mfma(
    const short* __restrict__ xb, const short* __restrict__ wb,
    short* __restrict__ qb, short* __restrict__ kb,
    float* __restrict__ vo, short* __restrict__ vt)
{
    const int t = threadIdx.x, l = t & 63, ww = t >> 6;
    const int quad = l >> 4, lc = l & 15;
    // XCD swizzle: nwg=882 = 8*110+2 -> chunks {111,111,110*6}
    const int P = blockIdx.x, xcd = P & 7, ii = P >> 3;
    const int start = (xcd < 2) ? xcd * 111 : 222 + (xcd - 2) * 110;
    const int orig = start + ii;
    const int bx = orig / 18, bn = orig % 18;

    const int m0 = bx * 128 + (ww >> 1) * 64;
    const int wsel = bn / 6;
    const int colbase = (bn % 6) * 128 + (ww & 1) * 64;
    const short* W = wb + (size_t)wsel * 589824;

    f32x4 acc[4][4] = {};
    const short* arow = xb + (size_t)(m0 + lc) * 768 + quad * 8;
    const short* brow = W  + (size_t)(colbase + lc) * 768 + quad * 8;

    for (int k0 = 0; k0 < 768; k0 += 32) {
        bf16x8 af[4], bf[4];
#pragma unroll
        for (int i = 0; i < 4; i++) af[i] = *(const bf16x8*)(arow + (size_t)i * 16 * 768 + k0);
#pragma unroll
        for (int j = 0; j < 4; j++) bf[j] = *(const bf16x8*)(brow + (size_t)j * 16 * 768 + k0);
#pragma unroll
        for (int i = 0; i < 4; i++)
#pragma unroll
            for (int j = 0; j < 4; j++)
                acc[i][j] = MFMA16(af[i], bf[j], acc[i][j]);
    }

#pragma unroll
    for (int i = 0; i < 4; i++) {
#pragma unroll
        for (int j = 0; j < 4; j++) {
            const int o = colbase + j * 16 + lc;
            const int h = o / DD, d = o % DD;
#pragma unroll
            for (int r = 0; r < 4; r++) {
                const int m = m0 + i * 16 + quad * 4 + r;
                const int b = m / NN, n = m % NN;
                const size_t bhnd = (((size_t)b * HH + h) * NN + n) * DD + d;
                const float v = acc[i][j][r];
                if (wsel == 0)      qb[bhnd] = f2bf(v);
                else if (wsel == 1) kb[bhnd] = f2bf(v);
                else {
                    __builtin_nontemporal_store(v, vo + bhnd);   // nothing re-reads vo
                    vt[((size_t)(b * HH + h) * DD + d) * NN + n] = f2bf(v);
                }
            }
        }
    }
}

// ---------------------------------------------------------------------------
// K2': fused QK^T + patch softmax + separable positional softmax + blend +
// attn write + PV. 1-D grid 6272, bh-major + XCD chunk swizzle (784 = 16
// full bh per XCD: the 49 row-blocks sharing a bh's K/V panels are L2-local).
// Softmax passes vectorized to f32x4 (12 iters + 16-col tail): ~4x fewer
// LDS/flat instructions, 16B NT attn stores.
// LDS: 16x812 fp32 Sbuf + 4x55 tables + 16x4 pmax = 53.1 KB -> 3 blocks/CU.
// ---------------------------------------------------------------------------
__global__ __launch_bounds__(256) void attn_pv_fused(
    const short* __restrict__ qb, const short* __restrict__ kb,
    const short* __restrict__ vt,
    const float* __restrict__ W_pos, const float* __restrict__ b_pos,
    const float* __restrict__ gating, float* __restrict__ attn,
    short* __restrict__ ob)
{
    const int t = threadIdx.x, l = t & 63, ww = t >> 6;
    const int quad = l >> 4, lc = l & 15;
    // XCD swizzle: nwg=6272 = 8*784 exactly -> orig = xcd*784 + P/8
    const int P = blockIdx.x;
    const int orig = (P & 7) * 784 + (P >> 3);
    const int bh = orig / 49, b = bh >> 4, h = bh & 15;
    const int row0 = (orig % 49) * 16;

    __shared__ __align__(16) float Sbuf[16][812];
    __shared__ float lxs[55], lys[55], fxs[55], fys[55];
    __shared__ float pmws[16][4];

    // zero-pad cols 784..799 (PV k-loop reads through 799)
    Sbuf[t >> 4][784 + (t & 15)] = 0.f;

    // ---- phase A: S strip = q(16x48) @ k^T, col-tiles split across waves,
    // next-tile K fragments prefetched, per-row max tracked in registers.
    const short* qrow = qb + ((size_t)bh * NN + row0 + lc) * DD;
    bf16x8 qf0 = *(const bf16x8*)(qrow + quad * 8);
    bf16x8 qf1 = (quad < 2) ? *(const bf16x8*)(qrow + 32 + quad * 8) : bzero();

    float pmax[4] = {-3e38f, -3e38f, -3e38f, -3e38f};
    {
        int ct = ww;
        const short* krow = kb + ((size_t)bh * NN + ct * 16 + lc) * DD;
        bf16x8 kf0 = *(const bf16x8*)(krow + quad * 8);
        bf16x8 kf1 = (quad < 2) ? *(const bf16x8*)(krow + 32 + quad * 8) : bzero();
        while (ct < 49) {
            const int nct = ct + 4;
            bf16x8 nk0 = bzero(), nk1 = bzero();
            if (nct < 49) {
                const short* nrow = kb + ((size_t)bh * NN + nct * 16 + lc) * DD;
                nk0 = *(const bf16x8*)(nrow + quad * 8);
                nk1 = (quad < 2) ? *(const bf16x8*)(nrow + 32 + quad * 8) : bzero();
            }
            f32x4 cc = {0.f, 0.f, 0.f, 0.f};
            cc = MFMA16(qf0, kf0, cc);
            cc = MFMA16(qf1, kf1, cc);
            const int c0 = ct * 16;
#pragma unroll
            for (int r = 0; r < 4; r++) {
                Sbuf[quad * 4 + r][c0 + lc] = cc[r] * SCALE;
                pmax[r] = fmaxf(pmax[r], cc[r]);
            }
            kf0 = nk0; kf1 = nk1; ct = nct;
        }
    }
    // per-row partial max across the 16 cols this quad-group owns
#pragma unroll
    for (int r = 0; r < 4; r++) {
        float v = pmax[r];
        v = fmaxf(v, __shfl_xor(v, 1));
        v = fmaxf(v, __shfl_xor(v, 2));
        v = fmaxf(v, __shfl_xor(v, 4));
        v = fmaxf(v, __shfl_xor(v, 8));
        if (lc == 0) pmws[quad * 4 + r][ww] = v;
    }

    // ---- separable positional logits: lx(d)=w0*d+w2*d^2, ly(d)=w1*d+w2*d^2
    // (b_pos cancels in softmax; exp(pl) = fx(dx)*fy(dy), denom = Sx*Sy)
    const float w0 = W_pos[h * 3], w1 = W_pos[h * 3 + 1], w2 = W_pos[h * 3 + 2];
    if (t < 55) {
        const float d = (float)(t - 27);
        lxs[t] = fmaf(w2, d * d, w0 * d);
    } else if (t >= 64 && t < 119) {
        const float d = (float)(t - 91);
        lys[t - 64] = fmaf(w2, d * d, w1 * d);
    }

    __syncthreads();

    // ---- per-axis max-normalized exp tables (overflow-safe: fx,fy <= 1)
    if (t < 55) {
        float m = lxs[0];
#pragma unroll
        for (int i = 1; i < 55; i++) m = fmaxf(m, lxs[i]);
        fxs[t] = __expf(lxs[t] - m);
    } else if (t >= 64 && t < 119) {
        float m = lys[0];
#pragma unroll
        for (int i = 1; i < 55; i++) m = fmaxf(m, lys[i]);
        fys[t - 64] = __expf(lys[t - 64] - m);
    }

    // ---- patch softmax: max from phase-A partials, f32x4 exp+sum pass
    const int r = t >> 4, c = t & 15;
    const int nrow = row0 + r;
    const int nx = nrow % 28, ny = nrow / 28;

    const float sm = SCALE * fmaxf(fmaxf(pmws[r][0], pmws[r][1]),
                                   fmaxf(pmws[r][2], pmws[r][3]));
    float se = 0.f;
#pragma unroll 4
    for (int s = 0; s < 12; s++) {
        f32x4 v = *(const f32x4*)&Sbuf[r][c * 4 + 64 * s];
        v[0] = __expf(v[0] - sm); v[1] = __expf(v[1] - sm);
        v[2] = __expf(v[2] - sm); v[3] = __expf(v[3] - sm);
        *(f32x4*)&Sbuf[r][c * 4 + 64 * s] = v;
        se += (v[0] + v[1]) + (v[2] + v[3]);
    }
    if (c < 4) {
        f32x4 v = *(const f32x4*)&Sbuf[r][768 + c * 4];
        v[0] = __expf(v[0] - sm); v[1] = __expf(v[1] - sm);
        v[2] = __expf(v[2] - sm); v[3] = __expf(v[3] - sm);
        *(f32x4*)&Sbuf[r][768 + c * 4] = v;
        se += (v[0] + v[1]) + (v[2] + v[3]);
    }
    se += __shfl_xor(se, 1);
    se += __shfl_xor(se, 2);
    se += __shfl_xor(se, 4);
    se += __shfl_xor(se, 8);
    const float inv = 1.f / se;
    const float g = 1.f / (1.f + __expf(-gating[h]));

    __syncthreads();   // fxs/fys visible

    // ---- positional denominator: Sx(nx)*Sy(ny), 28-term sums from tables
    float Sx = 0.f, Sy = 0.f;
#pragma unroll
    for (int mx = 0; mx < 28; mx++) Sx += fxs[mx - nx + 27];
#pragma unroll
    for (int my = 0; my < 28; my++) Sy += fys[my - ny + 27];
    const float ginv = (1.f - g) * inv;          // patch coefficient
    const float gp = g / (Sx * Sy);              // pos coefficient

    // ---- blend + f32x4 NT attn write (blend sums to 1: renorm dropped,
    // error ~1e-6 << tolerance). Keep blended row in LDS for PV.
    float* arow = attn + ((size_t)bh * NN + nrow) * NN;
    const float* fxp = fxs + 27 - nx;
    const float* fyp = fys + 27 - ny;
#define BLEND4(M0)                                                         \
    {                                                                      \
        const int m0_ = (M0);                                              \
        f32x4 v = *(const f32x4*)&Sbuf[r][m0_];                            \
        int mx = m0_ % 28, my = m0_ / 28;                                  \
        f32x4 a;                                                           \
        a[0] = fmaf(v[0], ginv, fxp[mx] * fyp[my] * gp);                   \
        if (++mx == 28) { mx = 0; my++; }                                  \
        a[1] = fmaf(v[1], ginv, fxp[mx] * fyp[my] * gp);                   \
        if (++mx == 28) { mx = 0; my++; }                                  \
        a[2] = fmaf(v[2], ginv, fxp[mx] * fyp[my] * gp);                   \
        if (++mx == 28) { mx = 0; my++; }                                  \
        a[3] = fmaf(v[3], ginv, fxp[mx] * fyp[my] * gp);                   \
        *(f32x4*)&Sbuf[r][m0_] = a;                                        \
        __builtin_nontemporal_store(a, (f32x4*)(arow + m0_));              \
    }
#pragma unroll 4
    for (int s = 0; s < 12; s++) BLEND4(c * 4 + 64 * s);
    if (c < 4) BLEND4(768 + c * 4);
#undef BLEND4

    __syncthreads();   // final attn strip visible to all waves

    // ---- PV: O(16x48) = attn(16x784) @ v(784x48). K-split: wave w handles
    // kt-range (each column converted to bf16 exactly once), then cross-wave
    // reduce via LDS partials aliased over the now-dead Sbuf.
    const short* vbase = vt + (size_t)bh * DD * NN;
    f32x4 acc[3] = {};
    {
        const int kt0 = ww * 6;                   // 6,6,6,7 split of 25
        const int kt1 = (ww == 3) ? 25 : kt0 + 6;
        for (int kt = kt0; kt < kt1; kt++) {
            const int k0 = kt * 32 + quad * 8;
            f32x4 a0 = *(const f32x4*)&Sbuf[lc][k0];
            f32x4 a1 = *(const f32x4*)&Sbuf[lc][k0 + 4];
            bf16x8 af = cvt8v(a0, a1);
#pragma unroll
            for (int j = 0; j < 3; j++) {
                bf16x8 bf = (k0 < NN)
                    ? *(const bf16x8*)(vbase + (size_t)(j * 16 + lc) * NN + k0)
                    : bzero();
                acc[j] = MFMA16(af, bf, acc[j]);
            }
        }
    }

    __syncthreads();   // everyone done reading Sbuf; safe to alias

    float* Pacc = &Sbuf[0][0];                    // [3 waves][3 j][64 lanes][4]
    if (ww > 0) {
#pragma unroll
        for (int j = 0; j < 3; j++)
            *(f32x4*)&Pacc[(((ww - 1) * 3 + j) * 64 + l) * 4] = acc[j];
    }

    __syncthreads();

    if (ww == 0) {
#pragma unroll
        for (int j = 0; j < 3; j++) {
#pragma unroll
            for (int w = 0; w < 3; w++)
                acc[j] += *(const f32x4*)&Pacc[((w * 3 + j) * 64 + l) * 4];
            const int d = h * DD + j * 16 + lc;
#pragma unroll
            for (int rr = 0; rr < 4; rr++) {
                const int rowi = row0 + quad * 4 + rr;
                ob[((size_t)b * NN + rowi) * CC + d] = f2bf(acc[j][rr]);
            }
        }
    }
}

// ---------------------------------------------------------------------------
// K4: out = ob @ Wproj^T + bias, bf16 MFMA NT GEMM. M=6272, N=768, K=768.
// 1-D grid 294, A-panel-major + XCD chunk swizzle (same rationale as K1).
// fp32 output (nontemporal scalar stores).
// ---------------------------------------------------------------------------
__global__ __launch_bounds__(256) void proj_mfma(
    const short* __restrict__ ob, const short* __restrict__ wb,
    const float* __restrict__ bias, float* __restrict__ out)
{
    const int t = threadIdx.x, l = t & 63, ww = t >> 6;
    const int quad = l >> 4, lc = l & 15;
    // XCD swizzle: nwg=294 = 8*36+6 -> chunks {37*6, 36*2}
    const int P = blockIdx.x, xcd = P & 7, ii = P >> 3;
    const int start = (xcd < 6) ? xcd * 37 : 222 + (xcd - 6) * 36;
    const int orig = start + ii;
    const int bx = orig / 6, by = orig % 6;

    const int m0 = bx * 128 + (ww >> 1) * 64;
    const int colbase = by * 128 + (ww & 1) * 64;
    const short* W = wb + (size_t)3 * 589824;   // Wproj

    f32x4 acc[4][4] = {};
    const short* arow = ob + (size_t)(m0 + lc) * 768 + quad * 8;
    const short* brow = W  + (size_t)(colbase + lc) * 768 + quad * 8;

    for (int k0 = 0; k0 < 768; k0 += 32) {
        bf16x8 af[4], bf[4];
#pragma unroll
        for (int i = 0; i < 4; i++) af[i] = *(const bf16x8*)(arow + (size_t)i * 16 * 768 + k0);
#pragma unroll
        for (int j = 0; j < 4; j++) bf[j] = *(const bf16x8*)(brow + (size_t)j * 16 * 768 + k0);
#pragma unroll
        for (int i = 0; i < 4; i++)
#pragma unroll
            for (int j = 0; j < 4; j++)
                acc[i][j] = MFMA16(af[i], bf[j], acc[i][j]);
    }

#pragma unroll
    for (int i = 0; i < 4; i++) {
#pragma unroll
        for (int j = 0; j < 4; j++) {
            const int o = colbase + j * 16 + lc;
            const float bo = bias[o];
#pragma unroll
            for (int r = 0; r < 4; r++) {
                const int m = m0 + i * 16 + quad * 4 + r;
                __builtin_nontemporal_store(acc[i][j][r] + bo, out + (size_t)m * CC + o);
            }
        }
    }
}

extern "C" void kernel_launch(void* const* d_in, const int* in_sizes, int n_in,
                              void* d_out, int out_size, void* d_ws, size_t ws_size,
                              hipStream_t stream)
{
    const float* x      = (const float*)d_in[0];
    const float* Wq     = (const float*)d_in[1];
    const float* Wk     = (const float*)d_in[2];
    const float* Wv     = (const float*)d_in[3];
    const float* Wproj  = (const float*)d_in[4];
    const float* b_proj = (const float*)d_in[5];
    const float* W_pos  = (const float*)d_in[6];
    const float* b_pos  = (const float*)d_in[7];
    const float* gating = (const float*)d_in[8];

    float* out  = (float*)d_out;
    short* ws   = (short*)d_ws;

    short* xb = ws + WS_XB;
    short* wb = ws + WS_WB;
    short* qb = ws + WS_QB;
    short* kb = ws + WS_KB;
    short* vt = ws + WS_VT;
    short* ob = ws + WS_OB;
    float* attn = out + ATTN_OFF;
    float* vout = out + V_OFF;

    hipLaunchKernelGGL(cast_kernel, dim3(7008), dim3(256), 0, stream,
                       x, Wq, Wk, Wv, Wproj, xb, wb);
    hipLaunchKernelGGL(qkv_mfma, dim3(882), dim3(256), 0, stream,
                       xb, wb, qb, kb, vout, vt);
    hipLaunchKernelGGL(attn_pv_fused, dim3(6272), dim3(256), 0, stream,
                       qb, kb, vt, W_pos, b_pos, gating, attn, ob);
    hipLaunchKernelGGL(proj_mfma, dim3(294), dim3(256), 0, stream,
                       ob, wb, b_proj, out);
}

// Round 5
// 621.147 us; speedup vs baseline: 1.3163x; 1.0126x over previous
//
#include <hip/hip_runtime.h>
#include <math.h>

#define BB 8
#define NN 784
#define CC 768
#define HH 16
#define DD 48
#define SCALE 0.14433756729740643f    // 48^-0.5

// d_out layout (floats): out [B,N,C] | attn [B,H,N,N] | v [B,H,N,D]
#define ATTN_OFF ((size_t)BB*NN*CC)                  // 4816896
#define V_OFF (ATTN_OFF + (size_t)BB*HH*NN*NN)       // 83492864

// workspace layout (shorts/bf16)
#define WS_XB ((size_t)0)                            // x bf16 [6272][768]
#define WS_WB ((size_t)4816896)                      // Wq|Wk|Wv|Wproj bf16, 4x[768][768]
#define WS_QB (WS_WB + (size_t)4*589824)             // q bf16 [B,H,N,D]
#define WS_KB (WS_QB + (size_t)4816896)              // k bf16 [B,H,N,D]
#define WS_VT (WS_KB + (size_t)4816896)              // v^T bf16 [B,H,D,N]
#define WS_OB (WS_VT + (size_t)4816896)              // attn@v bf16 [B,N,C]

using bf16x8 = __attribute__((ext_vector_type(8))) short;
using f32x4  = __attribute__((ext_vector_type(4))) float;

__device__ __forceinline__ short f2bf(float f) {
    union { float f; unsigned u; } uf; uf.f = f;
    unsigned u = uf.u;
    return (short)((u + 0x7FFFu + ((u >> 16) & 1u)) >> 16);   // RNE
}
__device__ __forceinline__ bf16x8 bzero() {
    bf16x8 z = {0,0,0,0,0,0,0,0};
    return z;
}
__device__ __forceinline__ bf16x8 cvt8v(f32x4 a, f32x4 b) {
    bf16x8 r;
    r[0]=f2bf(a[0]); r[1]=f2bf(a[1]); r[2]=f2bf(a[2]); r[3]=f2bf(a[3]);
    r[4]=f2bf(b[0]); r[5]=f2bf(b[1]); r[6]=f2bf(b[2]); r[7]=f2bf(b[3]);
    return r;
}
#define MFMA16(a,b,c) __builtin_amdgcn_mfma_f32_16x16x32_bf16((a),(b),(c),0,0,0)

// ---------------------------------------------------------------------------
// K0: cast x and the 4 weights to bf16 in ws. 4 floats / thread.
// ---------------------------------------------------------------------------
__global__ __launch_bounds__(256) void cast_kernel(
    const float* __restrict__ x, const float* __restrict__ Wq,
    const float* __restrict__ Wk, const float* __restrict__ Wv,
    const float* __restrict__ Wp, short* __restrict__ xb, short* __restrict__ wb)
{
    int idx = blockIdx.x * 256 + threadIdx.x;   // group of 4 elements
    const float* src;
    short* dst;
    if (idx < 1204224) {                         // x: 4816896/4
        src = x + (size_t)idx * 4;
        dst = xb + (size_t)idx * 4;
    } else {
        int j = idx - 1204224;
        int sel = j / 147456;                    // 589824/4
        size_t off = (size_t)(j % 147456) * 4;
        const float* W = (sel == 0) ? Wq : (sel == 1) ? Wk : (sel == 2) ? Wv : Wp;
        src = W + off;
        dst = wb + (size_t)sel * 589824 + off;
    }
    f32x4 v = *(const f32x4*)src;
    union { short s[4]; uint2 u; } o;
    o.s[0] = f2bf(v[0]); o.s[1] = f2bf(v[1]); o.s[2] = f2bf(v[2]); o.s[3] = f2bf(v[3]);
    *(uint2*)dst = o.u;
}

// ---------------------------------------------------------------------------
// K1: QKV projection, bf16 MFMA NT GEMM. M=6272, N=3*768, K=768.
// 1-D grid 882, A-panel-major order + bijective XCD chunk swizzle.
// q,k -> bf16 ws [B,H,N,D]; v -> fp32 d_out [B,H,N,D] + bf16 ws V^T [B,H,D,N].
// ---------------------------------------------------------------------------
__global__ __launch_bounds__(256) void qkv_mfma(
    const short* __restrict__ xb, const short* __restrict__ wb,
    short* __restrict__ qb, short* __restrict__ kb,
    float* __restrict__ vo, short* __restrict__ vt)
{
    const int t = threadIdx.x, l = t & 63, ww = t >> 6;
    const int quad = l >> 4, lc = l & 15;
    // XCD swizzle: nwg=882 = 8*110+2 -> chunks {111,111,110*6}
    const int P = blockIdx.x, xcd = P & 7, ii = P >> 3;
    const int start = (xcd < 2) ? xcd * 111 : 222 + (xcd - 2) * 110;
    const int orig = start + ii;
    const int bx = orig / 18, bn = orig % 18;

    const int m0 = bx * 128 + (ww >> 1) * 64;
    const int wsel = bn / 6;
    const int colbase = (bn % 6) * 128 + (ww & 1) * 64;
    const short* W = wb + (size_t)wsel * 589824;

    f32x4 acc[4][4] = {};
    const short* arow = xb + (size_t)(m0 + lc) * 768 + quad * 8;
    const short* brow = W  + (size_t)(colbase + lc) * 768 + quad * 8;

    for (int k0 = 0; k0 < 768; k0 += 32) {
        bf16x8 af[4], bf[4];
#pragma unroll
        for (int i = 0; i < 4; i++) af[i] = *(const bf16x8*)(arow + (size_t)i * 16 * 768 + k0);
#pragma unroll
        for (int j = 0; j < 4; j++) bf[j] = *(const bf16x8*)(brow + (size_t)j * 16 * 768 + k0);
#pragma unroll
        for (int i = 0; i < 4; i++)
#pragma unroll
            for (int j = 0; j < 4; j++)
                acc[i][j] = MFMA16(af[i], bf[j], acc[i][j]);
    }

#pragma unroll
    for (int i = 0; i < 4; i++) {
#pragma unroll
        for (int j = 0; j < 4; j++) {
            const int o = colbase + j * 16 + lc;
            const int h = o / DD, d = o % DD;
#pragma unroll
            for (int r = 0; r < 4; r++) {
                const int m = m0 + i * 16 + quad * 4 + r;
                const int b = m / NN, n = m % NN;
                const size_t bhnd = (((size_t)b * HH + h) * NN + n) * DD + d;
                const float v = acc[i][j][r];
                if (wsel == 0)      qb[bhnd] = f2bf(v);
                else if (wsel == 1) kb[bhnd] = f2bf(v);
                else {
                    __builtin_nontemporal_store(v, vo + bhnd);   // nothing re-reads vo
                    vt[((size_t)(b * HH + h) * DD + d) * NN + n] = f2bf(v);
                }
            }
        }
    }
}

// ---------------------------------------------------------------------------
// K2'': fused QK^T + softmax + separable positional softmax + blend + attn
// write + PV. This revision keeps the QK^T tiles in REGISTERS through the
// softmax (S touches LDS once, as exp'd values), builds the positional
// tables with an O(1) analytic normalizer (parabola max: endpoints or
// vertex; normalizer cancels in fx*fy/(Sx*Sy)), hoists the pos denominator
// to wave 0 (Sxs/Sys/rowfac built once per block instead of per thread),
// and splits the PV cross-wave reduce over 3 waves. 5 barriers (was 6).
// grid 6272 bh-major + XCD chunk swizzle.
// LDS: 16x812 Sbuf + tables/partials ~= 53.2 KB -> 3 blocks/CU.
// ---------------------------------------------------------------------------
__global__ __launch_bounds__(256, 3) void attn_pv_fused(
    const short* __restrict__ qb, const short* __restrict__ kb,
    const short* __restrict__ vt,
    const float* __restrict__ W_pos, const float* __restrict__ b_pos,
    const float* __restrict__ gating, float* __restrict__ attn,
    short* __restrict__ ob)
{
    const int t = threadIdx.x, l = t & 63, ww = t >> 6;
    const int quad = l >> 4, lc = l & 15;
    // XCD swizzle: nwg=6272 = 8*784 exactly -> orig = xcd*784 + P/8
    const int P = blockIdx.x;
    const int orig = (P & 7) * 784 + (P >> 3);
    const int bh = orig / 49, b = bh >> 4, h = bh & 15;
    const int row0 = (orig % 49) * 16;

    __shared__ __align__(16) float Sbuf[16][812];
    __shared__ float fxs[55], fys[55];
    __shared__ float Sxs[28], Sys[28], rowfac[16];
    __shared__ float pmws[16][4], sums[16][4];

    // zero-pad cols 784..799 (PV k-loop reads through 799)
    Sbuf[t >> 4][784 + (t & 15)] = 0.f;

    // ---- wave 0: pos tables + per-row denominators (overlaps other waves'
    // phase A). Analytic normalizer: lx(d)=w2*d^2+w0*d is a parabola; its
    // max over [-27,27] is max(lx(+-27)) if w2>=0 else the vertex value
    // -w0^2/(4w2). Any upper bound is valid (cancels in fx*fy/(Sx*Sy)).
    if (ww == 0) {
        const float w0 = W_pos[h * 3], w1 = W_pos[h * 3 + 1], w2 = W_pos[h * 3 + 2];
        float mx_ = fmaf(fabsf(w0), 27.f, w2 * 729.f);
        float my_ = fmaf(fabsf(w1), 27.f, w2 * 729.f);
        if (w2 < 0.f) {
            mx_ = fmaxf(mx_, -w0 * w0 / (4.f * w2));
            my_ = fmaxf(my_, -w1 * w1 / (4.f * w2));
        }
        if (l < 55) {
            const float d = (float)(l - 27);
            fxs[l] = __expf(fmaf(w2, d * d, w0 * d) - mx_);
            fys[l] = __expf(fmaf(w2, d * d, w1 * d) - my_);
        }
        if (l < 56) {                             // 0-27: Sx, 28-55: Sy
            const int n_ = (l < 28) ? l : l - 28;
            const float* tab = (l < 28) ? fxs : fys;
            float s = 0.f;
#pragma unroll
            for (int m = 0; m < 28; m++) s += tab[m - n_ + 27];
            if (l < 28) Sxs[n_] = s; else Sys[n_] = s;
        }
        if (l < 16) {
            const int nr = row0 + l;
            rowfac[l] = 1.f / (Sxs[nr % 28] * Sys[nr / 28]);
        }
    }

    // ---- phase A: S strip = q(16x48) @ k^T; 13 col-tiles per wave held in
    // registers; 1-deep K prefetch; per-row max tracked in registers.
    const short* qrow = qb + ((size_t)bh * NN + row0 + lc) * DD;
    bf16x8 qf0 = *(const bf16x8*)(qrow + quad * 8);
    bf16x8 qf1 = (quad < 2) ? *(const bf16x8*)(qrow + 32 + quad * 8) : bzero();

    const short* kbh = kb + (size_t)bh * NN * DD;
    f32x4 cc[13];
    float pmax[4] = {-3e38f, -3e38f, -3e38f, -3e38f};
    {
        bf16x8 kc0, kc1, kn0 = bzero(), kn1 = bzero();
        {
            const short* kr = kbh + (size_t)(ww * 16 + lc) * DD;
            kc0 = *(const bf16x8*)(kr + quad * 8);
            kc1 = (quad < 2) ? *(const bf16x8*)(kr + 32 + quad * 8) : bzero();
        }
#pragma unroll
        for (int i = 0; i < 13; i++) {
            const int ct = ww + 4 * i;
            if (ct < 49) {
                if (ct + 4 < 49) {
                    const short* kr = kbh + (size_t)((ct + 4) * 16 + lc) * DD;
                    kn0 = *(const bf16x8*)(kr + quad * 8);
                    kn1 = (quad < 2) ? *(const bf16x8*)(kr + 32 + quad * 8) : bzero();
                }
                f32x4 a = {0.f, 0.f, 0.f, 0.f};
                a = MFMA16(qf0, kc0, a);
                a = MFMA16(qf1, kc1, a);
                cc[i] = a;
#pragma unroll
                for (int r = 0; r < 4; r++) pmax[r] = fmaxf(pmax[r], a[r]);
                kc0 = kn0; kc1 = kn1;
            }
        }
    }
#pragma unroll
    for (int r = 0; r < 4; r++) {
        float v = pmax[r];
        v = fmaxf(v, __shfl_xor(v, 1));
        v = fmaxf(v, __shfl_xor(v, 2));
        v = fmaxf(v, __shfl_xor(v, 4));
        v = fmaxf(v, __shfl_xor(v, 8));
        if (lc == 0) pmws[quad * 4 + r][ww] = v;
    }

    __syncthreads();   // b1: pmws + tables + rowfac visible

    // ---- exp on registers; S hits LDS exactly once (as exp'd values);
    // per-row partial sums in registers.
    float sm4[4], ps[4];
#pragma unroll
    for (int r = 0; r < 4; r++) {
        sm4[r] = SCALE * fmaxf(fmaxf(pmws[quad * 4 + r][0], pmws[quad * 4 + r][1]),
                               fmaxf(pmws[quad * 4 + r][2], pmws[quad * 4 + r][3]));
        ps[r] = 0.f;
    }
#pragma unroll
    for (int i = 0; i < 13; i++) {
        const int ct = ww + 4 * i;
        if (ct < 49) {
#pragma unroll
            for (int r = 0; r < 4; r++) {
                const float e = __expf(fmaf(cc[i][r], SCALE, -sm4[r]));
                ps[r] += e;
                Sbuf[quad * 4 + r][ct * 16 + lc] = e;
            }
        }
    }
#pragma unroll
    for (int r = 0; r < 4; r++) {
        float v = ps[r];
        v += __shfl_xor(v, 1);
        v += __shfl_xor(v, 2);
        v += __shfl_xor(v, 4);
        v += __shfl_xor(v, 8);
        if (lc == 0) sums[quad * 4 + r][ww] = v;
    }

    __syncthreads();   // b2: exp'd S + sums visible

    // ---- blend + f32x4 NT attn write (blend sums to 1: renorm dropped,
    // error ~1e-6 << tolerance). Row-owner layout; keep blended row in LDS.
    const int r_ = t >> 4, c_ = t & 15;
    const int nrow = row0 + r_;
    const float g = 1.f / (1.f + __expf(-gating[h]));
    const float inv = 1.f / ((sums[r_][0] + sums[r_][1]) + (sums[r_][2] + sums[r_][3]));
    const float ginv = (1.f - g) * inv;          // patch coefficient
    const float gp = g * rowfac[r_];             // pos coefficient
    const int nx = nrow % 28, ny = nrow / 28;
    const float* fxp = fxs + 27 - nx;
    const float* fyp = fys + 27 - ny;
    float* arow = attn + ((size_t)bh * NN + nrow) * NN;
#define BLEND4(M0)                                                         \
    {                                                                      \
        const int m0_ = (M0);                                              \
        f32x4 v = *(const f32x4*)&Sbuf[r_][m0_];                           \
        int mx = m0_ % 28, my = m0_ / 28;                                  \
        f32x4 a;                                                           \
        a[0] = fmaf(v[0], ginv, fxp[mx] * fyp[my] * gp);                   \
        if (++mx == 28) { mx = 0; my++; }                                  \
        a[1] = fmaf(v[1], ginv, fxp[mx] * fyp[my] * gp);                   \
        if (++mx == 28) { mx = 0; my++; }                                  \
        a[2] = fmaf(v[2], ginv, fxp[mx] * fyp[my] * gp);                   \
        if (++mx == 28) { mx = 0; my++; }                                  \
        a[3] = fmaf(v[3], ginv, fxp[mx] * fyp[my] * gp);                   \
        *(f32x4*)&Sbuf[r_][m0_] = a;                                       \
        __builtin_nontemporal_store(a, (f32x4*)(arow + m0_));              \
    }
#pragma unroll 4
    for (int s = 0; s < 12; s++) BLEND4(c_ * 4 + 64 * s);
    if (c_ < 4) BLEND4(768 + c_ * 4);
#undef BLEND4

    __syncthreads();   // b3: final attn strip visible to all waves

    // ---- PV: O(16x48) = attn(16x784) @ v(784x48). K-split: wave w handles
    // a kt-range (each column converted to bf16 exactly once).
    const short* vbase = vt + (size_t)bh * DD * NN;
    f32x4 acc[3] = {};
    {
        const int kt0 = ww * 6;                   // 6,6,6,7 split of 25
        const int kt1 = (ww == 3) ? 25 : kt0 + 6;
        for (int kt = kt0; kt < kt1; kt++) {
            const int k0 = kt * 32 + quad * 8;
            f32x4 a0 = *(const f32x4*)&Sbuf[lc][k0];
            f32x4 a1 = *(const f32x4*)&Sbuf[lc][k0 + 4];
            bf16x8 af = cvt8v(a0, a1);
#pragma unroll
            for (int j = 0; j < 3; j++) {
                bf16x8 bf = (k0 < NN)
                    ? *(const bf16x8*)(vbase + (size_t)(j * 16 + lc) * NN + k0)
                    : bzero();
                acc[j] = MFMA16(af, bf, acc[j]);
            }
        }
    }

    __syncthreads();   // b4: everyone done reading Sbuf; safe to alias

    float* Pacc = &Sbuf[0][0];                    // [4 waves][3 j][64 lanes][4]
#pragma unroll
    for (int j = 0; j < 3; j++)
        *(f32x4*)&Pacc[((ww * 3 + j) * 64 + l) * 4] = acc[j];

    __syncthreads();   // b5

    // cross-wave reduce split over waves 0-2 (one j-tile each)
    if (ww < 3) {
        f32x4 s = {0.f, 0.f, 0.f, 0.f};
#pragma unroll
        for (int w = 0; w < 4; w++)
            s += *(const f32x4*)&Pacc[((w * 3 + ww) * 64 + l) * 4];
        const int d = h * DD + ww * 16 + lc;
#pragma unroll
        for (int rr = 0; rr < 4; rr++)
            ob[((size_t)b * NN + row0 + quad * 4 + rr) * CC + d] = f2bf(s[rr]);
    }
}

// ---------------------------------------------------------------------------
// K4: out = ob @ Wproj^T + bias, bf16 MFMA NT GEMM. M=6272, N=768, K=768.
// 1-D grid 294, A-panel-major + XCD chunk swizzle. fp32 output (NT).
// ---------------------------------------------------------------------------
__global__ __launch_bounds__(256) void proj_mfma(
    const short* __restrict__ ob, const short* __restrict__ wb,
    const float* __restrict__ bias, float* __restrict__ out)
{
    const int t = threadIdx.x, l = t & 63, ww = t >> 6;
    const int quad = l >> 4, lc = l & 15;
    // XCD swizzle: nwg=294 = 8*36+6 -> chunks {37*6, 36*2}
    const int P = blockIdx.x, xcd = P & 7, ii = P >> 3;
    const int start = (xcd < 6) ? xcd * 37 : 222 + (xcd - 6) * 36;
    const int orig = start + ii;
    const int bx = orig / 6, by = orig % 6;

    const int m0 = bx * 128 + (ww >> 1) * 64;
    const int colbase = by * 128 + (ww & 1) * 64;
    const short* W = wb + (size_t)3 * 589824;   // Wproj

    f32x4 acc[4][4] = {};
    const short* arow = ob + (size_t)(m0 + lc) * 768 + quad * 8;
    const short* brow = W  + (size_t)(colbase + lc) * 768 + quad * 8;

    for (int k0 = 0; k0 < 768; k0 += 32) {
        bf16x8 af[4], bf[4];
#pragma unroll
        for (int i = 0; i < 4; i++) af[i] = *(const bf16x8*)(arow + (size_t)i * 16 * 768 + k0);
#pragma unroll
        for (int j = 0; j < 4; j++) bf[j] = *(const bf16x8*)(brow + (size_t)j * 16 * 768 + k0);
#pragma unroll
        for (int i = 0; i < 4; i++)
#pragma unroll
            for (int j = 0; j < 4; j++)
                acc[i][j] = MFMA16(af[i], bf[j], acc[i][j]);
    }

#pragma unroll
    for (int i = 0; i < 4; i++) {
#pragma unroll
        for (int j = 0; j < 4; j++) {
            const int o = colbase + j * 16 + lc;
            const float bo = bias[o];
#pragma unroll
            for (int r = 0; r < 4; r++) {
                const int m = m0 + i * 16 + quad * 4 + r;
                __builtin_nontemporal_store(acc[i][j][r] + bo, out + (size_t)m * CC + o);
            }
        }
    }
}

extern "C" void kernel_launch(void* const* d_in, const int* in_sizes, int n_in,
                              void* d_out, int out_size, void* d_ws, size_t ws_size,
                              hipStream_t stream)
{
    const float* x      = (const float*)d_in[0];
    const float* Wq     = (const float*)d_in[1];
    const float* Wk     = (const float*)d_in[2];
    const float* Wv     = (const float*)d_in[3];
    const float* Wproj  = (const float*)d_in[4];
    const float* b_proj = (const float*)d_in[5];
    const float* W_pos  = (const float*)d_in[6];
    const float* b_pos  = (const float*)d_in[7];
    const float* gating = (const float*)d_in[8];

    float* out  = (float*)d_out;
    short* ws   = (short*)d_ws;

    short* xb = ws + WS_XB;
    short* wb = ws + WS_WB;
    short* qb = ws + WS_QB;
    short* kb = ws + WS_KB;
    short* vt = ws + WS_VT;
    short* ob = ws + WS_OB;
    float* attn = out + ATTN_OFF;
    float* vout = out + V_OFF;

    hipLaunchKernelGGL(cast_kernel, dim3(7008), dim3(256), 0, stream,
                       x, Wq, Wk, Wv, Wproj, xb, wb);
    hipLaunchKernelGGL(qkv_mfma, dim3(882), dim3(256), 0, stream,
                       xb, wb, qb, kb, vout, vt);
    hipLaunchKernelGGL(attn_pv_fused, dim3(6272), dim3(256), 0, stream,
                       qb, kb, vt, W_pos, b_pos, gating, attn, ob);
    hipLaunchKernelGGL(proj_mfma, dim3(294), dim3(256), 0, stream,
                       ob, wb, b_proj, out);
}